// Round 14
// baseline (234.922 us; speedup 1.0000x reference)
//
#include <hip/hip_runtime.h>
#include <math.h>

// Chamfer distance, B=4, H=W=128, HW=16384, threshold 0.1.
//
// r13 post-mortem: window levers exhausted (needed window ~= AWIN=768).
// Remaining controllable fat is the overhead chunk (~28-30us): scatter's
// 20-barrier Hillis-Steele scan and the 4-block reduce_out launch. r14:
// (1) hierarchical wave scan in scatter (shfl_up + wave0 scan, 3 barriers,
// integer-exact -> binstart bit-identical); (2) fuse reduce into pdist via
// last-block-per-batch (donecnt zeroed by scatter in-stream; writer blocks
// __threadfence() then count; 256th block re-runs the reduction with the
// EXACT original summation order: thread tid = original thread d*512+tid,
// same shfl tree, same wsum order -> bits identical). pdist math, bound
// machinery, compact: VERBATIM r13 (absmax-0.0 pedigree).
//
// ws layout (~5.1 MB):
//   [0,128)    int segcounts[8][4]
//   [256,+2MB) float4 pts[8][HW]     segmented semi-dense (seg s at s*4096)
//   [+512KB)   uint minarr[8][HW]    d^2 bits, slot-indexed
//   [+2MB)     float4 sorted[8][HW]  (x, y, z, slot_bits) rho-bucket order
//   [+32.8KB)  int binstart[8][1025]
//   [+128KB)   int hist[8][4][1024]
//   [+16B)     int donecnt[4]        per-batch pdist completion counters

#define B_ 4
#define HW_ 16384
#define THRESH 0.1f
#define BIGF 1e30f
#define EPS_ 1e-12f

#define SEGCAP 4096
#define NSEG 4
#define NBIN 1024
#define BINSCALE 1.0f    // bin = min(1023, rho); width 1, covers rho<1024
#define BINW 1.0f
#define RG 128           // rows per pdist block (2/lane -- window-optimal, r8)
#define NW 8             // waves per pdist block (512 threads)
#define AWIN 768         // phase-A window (cols); needed window ~700-750
#define PD_NGRP 128      // 128 groups x 128 rows covers n_from <= 16384

// ---------------- compact + bin histogram (r6, proven) ----------------
__global__ __launch_bounds__(1024)
void compact_kernel(const float* __restrict__ in1, const float* __restrict__ in2,
                    int* __restrict__ segcounts, float4* __restrict__ pts,
                    uint4* __restrict__ minarr4, int* __restrict__ histG) {
    int seg = blockIdx.x, combo = blockIdx.y;
    int b = combo >> 1, s = combo & 1;
    int tid = threadIdx.x, lane = tid & 63, wid = tid >> 6;
    const float* in = s ? in2 : in1;
    int ibase = seg * SEGCAP + tid * 4;
    float4 v = ((const float4*)(in + b * HW_))[(unsigned)ibase >> 2];
    float w0 = v.x - THRESH, w1 = v.y - THRESH, w2 = v.z - THRESH, w3 = v.w - THRESH;
    int a0 = w0 > 0.f, a1 = w1 > 0.f, a2 = w2 > 0.f, a3 = w3 > 0.f;

    unsigned int bb = __float_as_uint(BIGF);
    minarr4[(unsigned)(combo * HW_ + ibase) >> 2] = make_uint4(bb, bb, bb, bb);

    __shared__ int hist[NBIN];
    if (tid < NBIN) hist[tid] = 0;

    int c = a0 + a1 + a2 + a3;
    int incl = c;
#pragma unroll
    for (int o = 1; o < 64; o <<= 1) {
        int x = __shfl_up(incl, o, 64);
        if (lane >= o) incl += x;
    }
    int wexcl = incl - c;
    __shared__ int wtot[16], wpre[17];
    if (lane == 63) wtot[wid] = incl;
    __syncthreads();                             // covers hist init too
    if (tid == 0) {
        int run = 0;
#pragma unroll
        for (int ww = 0; ww < 16; ++ww) { wpre[ww] = run; run += wtot[ww]; }
        wpre[16] = run;
    }
    __syncthreads();
    int off = wpre[wid] + wexcl;
    float4* dst = pts + combo * HW_ + seg * SEGCAP;
    float wv[4] = {w0, w1, w2, w3};
    int   av[4] = {a0, a1, a2, a3};
#pragma unroll
    for (int u = 0; u < 4; ++u) {
        if (av[u]) {
            int i = ibase + u;
            float qx = (float)(i >> 7) * wv[u];
            float qy = (float)(i & 127) * wv[u];
            float zz = qx * qx + qy * qy;
            dst[off] = make_float4(qx, qy, zz, 0.0f);
            int bin = min(NBIN - 1, (int)(sqrtf(zz) * BINSCALE));
            atomicAdd(&hist[bin], 1);
            ++off;
        }
    }
    if (tid == 0) segcounts[combo * 4 + seg] = wpre[16];
    __syncthreads();
    if (tid < NBIN)
        histG[(combo * NSEG + seg) * NBIN + tid] = hist[tid];
}

// ---------------- scatter: wave-scan (3 barriers vs 20), zero donecnt ------
__global__ __launch_bounds__(1024)
void scatter_kernel(const int* __restrict__ segcounts, const float4* __restrict__ pts,
                    const int* __restrict__ histG, float4* __restrict__ sorted,
                    int* __restrict__ binstartG, int* __restrict__ donecnt) {
    int seg = blockIdx.x, combo = blockIdx.y;
    int tid = threadIdx.x, lane = tid & 63, wid = tid >> 6;
    if (seg == 0 && (combo & 1) == 0 && tid == 0)
        donecnt[combo >> 1] = 0;                 // before pdist in stream order
    __shared__ int h[NSEG][NBIN];
    __shared__ int cur[NBIN];
    __shared__ int wtot[16];
    for (int i = tid; i < NSEG * NBIN; i += 1024)
        h[i >> 10][i & (NBIN - 1)] = histG[combo * NSEG * NBIN + i];
    __syncthreads();
    // NBIN == 1024 == blockDim: each thread owns one bin. Hierarchical scan:
    // wave shfl_up scan + wave0 scans the 16 wave totals. Integer adds ->
    // bit-identical binstart vs the old Hillis-Steele (which had 20 barriers).
    int tot = h[0][tid] + h[1][tid] + h[2][tid] + h[3][tid];
    int v = tot;
#pragma unroll
    for (int o = 1; o < 64; o <<= 1) {
        int x = __shfl_up(v, o, 64);
        if (lane >= o) v += x;
    }
    if (lane == 63) wtot[wid] = v;
    __syncthreads();
    if (wid == 0) {
        int wv = (lane < 16) ? wtot[lane] : 0;
#pragma unroll
        for (int o = 1; o < 16; o <<= 1) {
            int x = __shfl_up(wv, o, 64);
            if (lane >= o) wv += x;
        }
        if (lane < 16) wtot[lane] = wv;          // inclusive wave sums
    }
    __syncthreads();
    int incl = v + (wid > 0 ? wtot[wid - 1] : 0);
    int excl = incl - tot;                       // exclusive bin start
    {
        int o2 = excl;
        for (int s2 = 0; s2 < seg; ++s2) o2 += h[s2][tid];   // seg-uniform
        cur[tid] = o2;
        if (seg == 0) binstartG[combo * (NBIN + 1) + tid] = excl;
    }
    if (seg == 0 && tid == NBIN - 1)
        binstartG[combo * (NBIN + 1) + NBIN] = incl;   // n_active
    __syncthreads();
    int c = segcounts[combo * 4 + seg];
    const float4* src = pts + combo * HW_ + seg * SEGCAP;
    for (int i = tid; i < c; i += 1024) {
        float4 p = src[i];
        int bin = min(NBIN - 1, (int)(sqrtf(p.z) * BINSCALE));
        int idx = atomicAdd(&cur[bin], 1);
        sorted[(size_t)combo * HW_ + idx] =
            make_float4(p.x, p.y, p.z, __uint_as_float((unsigned)(seg * SEGCAP + i)));
    }
}

// ---------------- pruned dist + fused last-block reduction -----------------
__global__ __launch_bounds__(512, 4)
void pdist_kernel(const float4* __restrict__ sorted, const int* __restrict__ binstart,
                  const int* __restrict__ segcounts, unsigned int* __restrict__ minarr,
                  float* __restrict__ out, int* __restrict__ donecnt) {
    int grp = blockIdx.x, combo = blockIdx.y;
    int tid = threadIdx.x, lane = tid & 63, w = tid >> 6;
    int tc = combo ^ 1;
    int n_from = binstart[combo * (NBIN + 1) + NBIN];
    int n_to   = binstart[tc * (NBIN + 1) + NBIN];
    int rbase = grp * RG;
    // block-uniform work guard (early-exit blocks must still reach the count)
    bool doWork = (n_from > 0) && (n_to > 0) && (rbase < n_from);

    __shared__ __align__(16) float bx[NW][64], by[NW][64], bz[NW][64];
    __shared__ float mW[NW][RG];

    if (doWork) {
        const float4* __restrict__ rows = sorted + (size_t)combo * HW_;
        const float4* __restrict__ cols = sorted + (size_t)tc * HW_;

        int r0 = rbase + lane, r1 = rbase + 64 + lane;
        bool v0 = r0 < n_from, v1 = r1 < n_from;
        float4 P0 = rows[min(r0, n_from - 1)];
        float4 P1 = rows[min(r1, n_from - 1)];
        float npx0 = -2.0f * P0.x, npy0 = -2.0f * P0.y, p20 = P0.z;
        float npx1 = -2.0f * P1.x, npy1 = -2.0f * P1.y, p21 = P1.z;
        unsigned int slot0 = __float_as_uint(P0.w);
        unsigned int slot1 = __float_as_uint(P1.w);
        float m0 = BIGF, m1 = BIGF;

        // group rho bounds from BIN BOUNDARIES (order-independent -- r6 fix)
        int blo_r = min(NBIN - 1, (int)(sqrtf(rows[rbase].z) * BINSCALE));
        int bhi_r = min(NBIN - 1, (int)(sqrtf(rows[min(rbase + RG - 1, n_from - 1)].z) * BINSCALE));
        float rho_lo = (float)blo_r * BINW;      // every row rho >= rho_lo
        float rho_hi = (float)(bhi_r + 1) * BINW;// every row rho <  rho_hi

        // phase-A window centered on the rows' bin-range midpoint (r8)
        int jmid = (binstart[tc * (NBIN + 1) + blo_r]
                    + binstart[tc * (NBIN + 1) + min(bhi_r + 1, NBIN)]) >> 1;
        int aHi = min(n_to, jmid + AWIN / 2);
        int aLo = max(0, aHi - AWIN);
        aHi = min(n_to, aLo + AWIN);

        auto ld = [&](int jb) -> float4 {        // clamped batch element load
            int j = jb + lane;
            return (j < n_to) ? cols[j] : make_float4(0.0f, 0.0f, BIGF, 0.0f);
        };
        // wave-uniform LDS broadcast inner loop; math VERBATIM dense bits.
        auto proc = [&](float4 qc) {
            bx[w][lane] = qc.x; by[w][lane] = qc.y; bz[w][lane] = qc.z;
            const float4* X = (const float4*)bx[w];
            const float4* Y = (const float4*)by[w];
            const float4* Z = (const float4*)bz[w];
#pragma unroll
            for (int q4 = 0; q4 < 16; ++q4) {
                float4 qx = X[q4], qy = Y[q4], qz = Z[q4];
                float t0 = fmaf(qy.x, npy0, fmaf(qx.x, npx0, qz.x));
                float u1 = fmaf(qy.y, npy0, fmaf(qx.y, npx0, qz.y));
                m0 = fminf(m0, fminf(t0, u1));
                float u2 = fmaf(qy.z, npy0, fmaf(qx.z, npx0, qz.z));
                float u3 = fmaf(qy.w, npy0, fmaf(qx.w, npx0, qz.w));
                m0 = fminf(m0, fminf(u2, u3));
                float s0 = fmaf(qy.x, npy1, fmaf(qx.x, npx1, qz.x));
                float s1 = fmaf(qy.y, npy1, fmaf(qx.y, npx1, qz.y));
                m1 = fminf(m1, fminf(s0, s1));
                float s2 = fmaf(qy.z, npy1, fmaf(qx.z, npx1, qz.z));
                float s3 = fmaf(qy.w, npy1, fmaf(qx.w, npx1, qz.w));
                m1 = fminf(m1, fminf(s2, s3));
            }
        };

        // ---- phase A: fixed window, wave-interleaved, prefetched ----
        int nbA = (aHi - aLo + 63) >> 6;
        float4 qn = (w < nbA) ? ld(aLo + (w << 6))
                              : make_float4(0.0f, 0.0f, BIGF, 0.0f);
        for (int bi = w; bi < nbA; bi += NW) {
            float4 qc = qn;
            if (bi + NW < nbA) qn = ld(aLo + ((bi + NW) << 6));
            proc(qc);
        }

        mW[w][lane] = m0; mW[w][64 + lane] = m1;
        __syncthreads();
        float c0 = mW[0][lane], c1 = mW[0][64 + lane];
#pragma unroll
        for (int ww = 1; ww < NW; ++ww) {
            c0 = fminf(c0, mW[ww][lane]);
            c1 = fminf(c1, mW[ww][64 + lane]);
        }
        float md0 = v0 ? fmaxf(c0 + p20, 0.0f) : -1.0f;
        float md1 = v1 ? fmaxf(c1 + p21, 0.0f) : -1.0f;
        float g = fmaxf(md0, md1);               // group md_max via wave reduce
#pragma unroll
        for (int o = 1; o < 64; o <<= 1) g = fmaxf(g, __shfl_xor(g, o));

        // exclusion bound (r6 margin family, proven absmax==0)
        float S = sqrtf((g + 1.0f) * (1.0f / 0.99f)) * 1.001f;
        int b_lo = max(0, (int)((rho_lo - S) * BINSCALE) - 1);
        int b_hi = min(NBIN, (int)((rho_hi + S) * BINSCALE) + 2);
        int jlo2 = binstart[tc * (NBIN + 1) + b_lo];
        int jhi2 = binstart[tc * (NBIN + 1) + b_hi];

        // ---- phase B: residual, check-free, prefetched ----
        m0 = c0; m1 = c1;
        int nbL = (max(0, aLo - jlo2) + 63) >> 6;
        int nbR = (max(0, jhi2 - aHi) + 63) >> 6;
        int nbB = nbL + nbR;
        auto jbB = [&](int bi) {
            return (bi < nbL) ? (jlo2 + (bi << 6)) : (aHi + ((bi - nbL) << 6));
        };
        qn = (w < nbB) ? ld(jbB(w)) : make_float4(0.0f, 0.0f, BIGF, 0.0f);
        for (int bi = w; bi < nbB; bi += NW) {
            float4 qc = qn;
            if (bi + NW < nbB) qn = ld(jbB(bi + NW));
            proc(qc);                            // overlap cols: min-idempotent
        }
        __syncthreads();                         // phase-A mW reads all done
        mW[w][lane] = m0; mW[w][64 + lane] = m1;
        __syncthreads();
        if (w == 0) {
            float f0 = mW[0][lane], f1 = mW[0][64 + lane];
#pragma unroll
            for (int ww = 1; ww < NW; ++ww) {
                f0 = fminf(f0, mW[ww][lane]);
                f1 = fminf(f1, mW[ww][64 + lane]);
            }
            if (v0) minarr[combo * HW_ + slot0] = __float_as_uint(fmaxf(f0 + p20, 0.0f));
            if (v1) minarr[combo * HW_ + slot1] = __float_as_uint(fmaxf(f1 + p21, 0.0f));
        }
    }

    // ---- last-block-per-batch fused reduction (EXACT original sum order) --
    int bb = combo >> 1;
    __threadfence();                             // release this block's stores
    __syncthreads();                             // order fences before count
    __shared__ int lastS;
    if (tid == 0)
        lastS = (atomicAdd(&donecnt[bb], 1) == 2 * PD_NGRP - 1);
    __syncthreads();
    if (!lastS) return;
    __threadfence();                             // acquire: all stores visible

    __shared__ float wsumA[NW], wsumB[NW];
    float s01[2];
#pragma unroll
    for (int d = 0; d < 2; ++d) {
        int cmb = bb * 2 + d;
        float acc = 0.0f;                        // == original thread d*512+tid
        for (int s = 0; s < NSEG; ++s) {
            int c = segcounts[cmb * 4 + s];
            const unsigned int* ma = minarr + cmb * HW_ + s * SEGCAP;
            for (int r = tid; r < c; r += 512)
                acc += sqrtf(fmaxf(__uint_as_float(ma[r]), EPS_));
        }
#pragma unroll
        for (int o = 32; o >= 1; o >>= 1) acc += __shfl_down(acc, o);
        if (lane == 0) { if (d == 0) wsumA[w] = acc; else wsumB[w] = acc; }
    }
    __syncthreads();
    if (tid == 0) {
        float s0 = 0.0f, s1 = 0.0f;
#pragma unroll
        for (int ww = 0; ww < NW; ++ww) s0 += wsumA[ww];   // == old w=0..7
#pragma unroll
        for (int ww = 0; ww < NW; ++ww) s1 += wsumB[ww];   // == old w=8..15
        int n0 = 0, n1 = 0;
#pragma unroll
        for (int s = 0; s < NSEG; ++s) {
            n0 += segcounts[(bb * 2) * 4 + s];
            n1 += segcounts[(bb * 2 + 1) * 4 + s];
        }
        out[bb] = (n0 > 0 && n1 > 0)
                  ? s0 / (float)n0 + s1 / (float)n1
                  : 1.0e6f;
    }
}

extern "C" void kernel_launch(void* const* d_in, const int* in_sizes, int n_in,
                              void* d_out, int out_size, void* d_ws, size_t ws_size,
                              hipStream_t stream) {
    const float* in1 = (const float*)d_in[0];
    const float* in2 = (const float*)d_in[1];
    float* out = (float*)d_out;
    char* ws = (char*)d_ws;
    int* segcounts = (int*)ws;
    float4* pts = (float4*)(ws + 256);
    size_t minoff = 256 + (size_t)8 * HW_ * sizeof(float4);
    unsigned int* minarr = (unsigned int*)(ws + minoff);
    size_t sortoff = minoff + (size_t)8 * HW_ * sizeof(unsigned int);
    float4* sorted = (float4*)(ws + sortoff);
    size_t binoff = sortoff + (size_t)8 * HW_ * sizeof(float4);
    int* binstart = (int*)(ws + binoff);
    size_t histoff = binoff + (size_t)8 * (NBIN + 1) * sizeof(int);
    int* histG = (int*)(ws + histoff);
    size_t doneoff = histoff + (size_t)8 * NSEG * NBIN * sizeof(int);
    int* donecnt = (int*)(ws + doneoff);

    hipLaunchKernelGGL(compact_kernel, dim3(NSEG, 8), dim3(1024), 0, stream,
                       in1, in2, segcounts, pts, (uint4*)minarr, histG);
    hipLaunchKernelGGL(scatter_kernel, dim3(NSEG, 8), dim3(1024), 0, stream,
                       segcounts, pts, histG, sorted, binstart, donecnt);
    hipLaunchKernelGGL(pdist_kernel, dim3(PD_NGRP, 8), dim3(512), 0, stream,
                       sorted, binstart, segcounts, minarr, out, donecnt);
}

// Round 15
// 78.629 us; speedup vs baseline: 2.9877x; 2.9877x over previous
//
#include <hip/hip_runtime.h>
#include <math.h>

// Chamfer distance, B=4, H=W=128, HW=16384, threshold 0.1.
//
// r14 post-mortem: last-block fused reduction CATASTROPHIC (79->235us).
// pdist 183us @ 2.4% VALU: __threadfence() is device-scope, and MI355X
// per-XCD L2s are non-coherent -> every fence = L2 writeback/invalidate;
// 2048 blocks x fence = serialized writeback storm. Cross-block handoff
// on this chip belongs at KERNEL BOUNDARIES (implicit barrier+coherence),
// not in-kernel fences. r15: revert the fusion wholesale (separate 4-block
// reduce_out, no donecnt/fences = r13 exactly) but KEEP r14's independent
// win: hierarchical wave-scan in scatter (3 barriers vs 20, integer adds
// -> binstart bit-identical; proven absmax 0.0 in r14).
//
// ws layout (~5.1 MB):
//   [0,128)    int segcounts[8][4]
//   [256,+2MB) float4 pts[8][HW]     segmented semi-dense (seg s at s*4096)
//   [+512KB)   uint minarr[8][HW]    d^2 bits, slot-indexed
//   [+2MB)     float4 sorted[8][HW]  (x, y, z, slot_bits) rho-bucket order
//   [+32.8KB)  int binstart[8][1025]
//   [+128KB)   int hist[8][4][1024]

#define B_ 4
#define HW_ 16384
#define THRESH 0.1f
#define BIGF 1e30f
#define EPS_ 1e-12f

#define SEGCAP 4096
#define NSEG 4
#define NBIN 1024
#define BINSCALE 1.0f    // bin = min(1023, rho); width 1, covers rho<1024
#define BINW 1.0f
#define RG 128           // rows per pdist block (2/lane -- window-optimal, r8)
#define NW 8             // waves per pdist block (512 threads)
#define AWIN 768         // phase-A window (cols); needed window ~700-750
#define PD_NGRP 128      // 128 groups x 128 rows covers n_from <= 16384

// ---------------- compact + bin histogram (r6, proven) ----------------
__global__ __launch_bounds__(1024)
void compact_kernel(const float* __restrict__ in1, const float* __restrict__ in2,
                    int* __restrict__ segcounts, float4* __restrict__ pts,
                    uint4* __restrict__ minarr4, int* __restrict__ histG) {
    int seg = blockIdx.x, combo = blockIdx.y;
    int b = combo >> 1, s = combo & 1;
    int tid = threadIdx.x, lane = tid & 63, wid = tid >> 6;
    const float* in = s ? in2 : in1;
    int ibase = seg * SEGCAP + tid * 4;
    float4 v = ((const float4*)(in + b * HW_))[(unsigned)ibase >> 2];
    float w0 = v.x - THRESH, w1 = v.y - THRESH, w2 = v.z - THRESH, w3 = v.w - THRESH;
    int a0 = w0 > 0.f, a1 = w1 > 0.f, a2 = w2 > 0.f, a3 = w3 > 0.f;

    unsigned int bb = __float_as_uint(BIGF);
    minarr4[(unsigned)(combo * HW_ + ibase) >> 2] = make_uint4(bb, bb, bb, bb);

    __shared__ int hist[NBIN];
    if (tid < NBIN) hist[tid] = 0;

    int c = a0 + a1 + a2 + a3;
    int incl = c;
#pragma unroll
    for (int o = 1; o < 64; o <<= 1) {
        int x = __shfl_up(incl, o, 64);
        if (lane >= o) incl += x;
    }
    int wexcl = incl - c;
    __shared__ int wtot[16], wpre[17];
    if (lane == 63) wtot[wid] = incl;
    __syncthreads();                             // covers hist init too
    if (tid == 0) {
        int run = 0;
#pragma unroll
        for (int ww = 0; ww < 16; ++ww) { wpre[ww] = run; run += wtot[ww]; }
        wpre[16] = run;
    }
    __syncthreads();
    int off = wpre[wid] + wexcl;
    float4* dst = pts + combo * HW_ + seg * SEGCAP;
    float wv[4] = {w0, w1, w2, w3};
    int   av[4] = {a0, a1, a2, a3};
#pragma unroll
    for (int u = 0; u < 4; ++u) {
        if (av[u]) {
            int i = ibase + u;
            float qx = (float)(i >> 7) * wv[u];
            float qy = (float)(i & 127) * wv[u];
            float zz = qx * qx + qy * qy;
            dst[off] = make_float4(qx, qy, zz, 0.0f);
            int bin = min(NBIN - 1, (int)(sqrtf(zz) * BINSCALE));
            atomicAdd(&hist[bin], 1);
            ++off;
        }
    }
    if (tid == 0) segcounts[combo * 4 + seg] = wpre[16];
    __syncthreads();
    if (tid < NBIN)
        histG[(combo * NSEG + seg) * NBIN + tid] = hist[tid];
}

// ---------------- scatter: hierarchical wave scan (3 barriers) -------------
__global__ __launch_bounds__(1024)
void scatter_kernel(const int* __restrict__ segcounts, const float4* __restrict__ pts,
                    const int* __restrict__ histG, float4* __restrict__ sorted,
                    int* __restrict__ binstartG) {
    int seg = blockIdx.x, combo = blockIdx.y;
    int tid = threadIdx.x, lane = tid & 63, wid = tid >> 6;
    __shared__ int h[NSEG][NBIN];
    __shared__ int cur[NBIN];
    __shared__ int wtot[16];
    for (int i = tid; i < NSEG * NBIN; i += 1024)
        h[i >> 10][i & (NBIN - 1)] = histG[combo * NSEG * NBIN + i];
    __syncthreads();
    // NBIN == 1024 == blockDim: each thread owns one bin. Wave shfl_up scan
    // + wave0 scans the 16 wave totals. Integer adds -> binstart
    // bit-identical to the old 20-barrier Hillis-Steele (r14-verified).
    int tot = h[0][tid] + h[1][tid] + h[2][tid] + h[3][tid];
    int v = tot;
#pragma unroll
    for (int o = 1; o < 64; o <<= 1) {
        int x = __shfl_up(v, o, 64);
        if (lane >= o) v += x;
    }
    if (lane == 63) wtot[wid] = v;
    __syncthreads();
    if (wid == 0) {
        int wv = (lane < 16) ? wtot[lane] : 0;
#pragma unroll
        for (int o = 1; o < 16; o <<= 1) {
            int x = __shfl_up(wv, o, 64);
            if (lane >= o) wv += x;
        }
        if (lane < 16) wtot[lane] = wv;          // inclusive wave sums
    }
    __syncthreads();
    int incl = v + (wid > 0 ? wtot[wid - 1] : 0);
    int excl = incl - tot;                       // exclusive bin start
    {
        int o2 = excl;
        for (int s2 = 0; s2 < seg; ++s2) o2 += h[s2][tid];   // seg-uniform
        cur[tid] = o2;
        if (seg == 0) binstartG[combo * (NBIN + 1) + tid] = excl;
    }
    if (seg == 0 && tid == NBIN - 1)
        binstartG[combo * (NBIN + 1) + NBIN] = incl;   // n_active
    __syncthreads();
    int c = segcounts[combo * 4 + seg];
    const float4* src = pts + combo * HW_ + seg * SEGCAP;
    for (int i = tid; i < c; i += 1024) {
        float4 p = src[i];
        int bin = min(NBIN - 1, (int)(sqrtf(p.z) * BINSCALE));
        int idx = atomicAdd(&cur[bin], 1);
        sorted[(size_t)combo * HW_ + idx] =
            make_float4(p.x, p.y, p.z, __uint_as_float((unsigned)(seg * SEGCAP + i)));
    }
}

// ---------------- pruned dist: 8 waves/block, 128 rows, 2 phases (r13) -----
__global__ __launch_bounds__(512, 4)   // VGPR cap 128: prefetch fits, no spill
void pdist_kernel(const float4* __restrict__ sorted, const int* __restrict__ binstart,
                  unsigned int* __restrict__ minarr) {
    int grp = blockIdx.x, combo = blockIdx.y;
    int tid = threadIdx.x, lane = tid & 63, w = tid >> 6;
    int tc = combo ^ 1;
    int n_from = binstart[combo * (NBIN + 1) + NBIN];
    int n_to   = binstart[tc * (NBIN + 1) + NBIN];
    if (n_from <= 0 || n_to <= 0) return;        // reduce_out emits sentinel
    int rbase = grp * RG;
    if (rbase >= n_from) return;                 // block-uniform

    const float4* __restrict__ rows = sorted + (size_t)combo * HW_;
    const float4* __restrict__ cols = sorted + (size_t)tc * HW_;

    int r0 = rbase + lane, r1 = rbase + 64 + lane;
    bool v0 = r0 < n_from, v1 = r1 < n_from;
    float4 P0 = rows[min(r0, n_from - 1)];
    float4 P1 = rows[min(r1, n_from - 1)];
    float npx0 = -2.0f * P0.x, npy0 = -2.0f * P0.y, p20 = P0.z;
    float npx1 = -2.0f * P1.x, npy1 = -2.0f * P1.y, p21 = P1.z;
    unsigned int slot0 = __float_as_uint(P0.w);
    unsigned int slot1 = __float_as_uint(P1.w);
    float m0 = BIGF, m1 = BIGF;

    // group rho bounds from BIN BOUNDARIES (order-independent -- r6 fix)
    int blo_r = min(NBIN - 1, (int)(sqrtf(rows[rbase].z) * BINSCALE));
    int bhi_r = min(NBIN - 1, (int)(sqrtf(rows[min(rbase + RG - 1, n_from - 1)].z) * BINSCALE));
    float rho_lo = (float)blo_r * BINW;          // every row rho >= rho_lo
    float rho_hi = (float)(bhi_r + 1) * BINW;    // every row rho <  rho_hi

    // phase-A window centered on the rows' bin-range midpoint (r8)
    int jmid = (binstart[tc * (NBIN + 1) + blo_r]
                + binstart[tc * (NBIN + 1) + min(bhi_r + 1, NBIN)]) >> 1;
    int aHi = min(n_to, jmid + AWIN / 2);
    int aLo = max(0, aHi - AWIN);
    aHi = min(n_to, aLo + AWIN);

    __shared__ __align__(16) float bx[NW][64], by[NW][64], bz[NW][64];
    __shared__ float mW[NW][RG];

    auto ld = [&](int jb) -> float4 {            // clamped batch element load
        int j = jb + lane;
        return (j < n_to) ? cols[j] : make_float4(0.0f, 0.0f, BIGF, 0.0f);
    };
    // stage a preloaded batch into this wave's LDS stripe and min-reduce.
    // Reads are wave-uniform broadcasts (cheap -- r11 proved the LDS pipe
    // is not the bottleneck). Inner math VERBATIM dense -> same bits.
    auto proc = [&](float4 qc) {
        bx[w][lane] = qc.x; by[w][lane] = qc.y; bz[w][lane] = qc.z;
        const float4* X = (const float4*)bx[w];
        const float4* Y = (const float4*)by[w];
        const float4* Z = (const float4*)bz[w];
#pragma unroll
        for (int q4 = 0; q4 < 16; ++q4) {
            float4 qx = X[q4], qy = Y[q4], qz = Z[q4];
            float t0 = fmaf(qy.x, npy0, fmaf(qx.x, npx0, qz.x));
            float u1 = fmaf(qy.y, npy0, fmaf(qx.y, npx0, qz.y));
            m0 = fminf(m0, fminf(t0, u1));
            float u2 = fmaf(qy.z, npy0, fmaf(qx.z, npx0, qz.z));
            float u3 = fmaf(qy.w, npy0, fmaf(qx.w, npx0, qz.w));
            m0 = fminf(m0, fminf(u2, u3));
            float s0 = fmaf(qy.x, npy1, fmaf(qx.x, npx1, qz.x));
            float s1 = fmaf(qy.y, npy1, fmaf(qx.y, npx1, qz.y));
            m1 = fminf(m1, fminf(s0, s1));
            float s2 = fmaf(qy.z, npy1, fmaf(qx.z, npx1, qz.z));
            float s3 = fmaf(qy.w, npy1, fmaf(qx.w, npx1, qz.w));
            m1 = fminf(m1, fminf(s2, s3));
        }
    };

    // ---- phase A: fixed window, wave-interleaved, prefetched ----
    int nbA = (aHi - aLo + 63) >> 6;
    float4 qn = (w < nbA) ? ld(aLo + (w << 6))
                          : make_float4(0.0f, 0.0f, BIGF, 0.0f);
    for (int bi = w; bi < nbA; bi += NW) {
        float4 qc = qn;
        if (bi + NW < nbA) qn = ld(aLo + ((bi + NW) << 6));  // hide under FMAs
        proc(qc);
    }

    mW[w][lane] = m0; mW[w][64 + lane] = m1;
    __syncthreads();
    float c0 = mW[0][lane], c1 = mW[0][64 + lane];
#pragma unroll
    for (int ww = 1; ww < NW; ++ww) {
        c0 = fminf(c0, mW[ww][lane]);
        c1 = fminf(c1, mW[ww][64 + lane]);
    }
    float md0 = v0 ? fmaxf(c0 + p20, 0.0f) : -1.0f;
    float md1 = v1 ? fmaxf(c1 + p21, 0.0f) : -1.0f;
    float g = fmaxf(md0, md1);                   // group md_max via wave reduce
#pragma unroll
    for (int o = 1; o < 64; o <<= 1) g = fmaxf(g, __shfl_xor(g, o));
    // identical in every wave/lane -> identical window on all threads

    // exclusion bound (r6 margin family, proven absmax==0): include every
    // col bin not provably excludable for any row; widen for float slop.
    float S = sqrtf((g + 1.0f) * (1.0f / 0.99f)) * 1.001f;
    int b_lo = max(0, (int)((rho_lo - S) * BINSCALE) - 1);
    int b_hi = min(NBIN, (int)((rho_hi + S) * BINSCALE) + 2);
    int jlo2 = binstart[tc * (NBIN + 1) + b_lo];
    int jhi2 = binstart[tc * (NBIN + 1) + b_hi];

    // ---- phase B: residual [jlo2,aLo) + [aHi,jhi2), check-free, prefetched
    m0 = c0; m1 = c1;
    int nbL = (max(0, aLo - jlo2) + 63) >> 6;
    int nbR = (max(0, jhi2 - aHi) + 63) >> 6;
    int nbB = nbL + nbR;
    auto jbB = [&](int bi) {
        return (bi < nbL) ? (jlo2 + (bi << 6)) : (aHi + ((bi - nbL) << 6));
    };
    qn = (w < nbB) ? ld(jbB(w)) : make_float4(0.0f, 0.0f, BIGF, 0.0f);
    for (int bi = w; bi < nbB; bi += NW) {
        float4 qc = qn;
        if (bi + NW < nbB) qn = ld(jbB(bi + NW));
        proc(qc);                                // overlap cols: min-idempotent
    }
    __syncthreads();                             // phase-A mW reads all done
    mW[w][lane] = m0; mW[w][64 + lane] = m1;
    __syncthreads();
    if (w == 0) {
        float f0 = mW[0][lane], f1 = mW[0][64 + lane];
#pragma unroll
        for (int ww = 1; ww < NW; ++ww) {
            f0 = fminf(f0, mW[ww][lane]);
            f1 = fminf(f1, mW[ww][64 + lane]);
        }
        if (v0) minarr[combo * HW_ + slot0] = __float_as_uint(fmaxf(f0 + p20, 0.0f));
        if (v1) minarr[combo * HW_ + slot1] = __float_as_uint(fmaxf(f1 + p21, 0.0f));
    }
}

// ---------------- reduce (unchanged: defines the absmax==0 sum order) -------
__global__ void reduce_out_kernel(const int* __restrict__ segcounts,
                                  const unsigned int* __restrict__ minarr,
                                  float* __restrict__ out) {
    int b = blockIdx.x;
    int tid = threadIdx.x;
    int d = tid >> 9;
    int t = tid & 511;
    int combo = b * 2 + d;

    float acc = 0.0f;
    for (int s = 0; s < NSEG; ++s) {
        int c = segcounts[combo * 4 + s];
        const unsigned int* ma = minarr + combo * HW_ + s * SEGCAP;
        for (int r = t; r < c; r += 512)
            acc += sqrtf(fmaxf(__uint_as_float(ma[r]), EPS_));
    }
#pragma unroll
    for (int o = 32; o >= 1; o >>= 1) acc += __shfl_down(acc, o);

    __shared__ float wsum[16];
    if ((tid & 63) == 0) wsum[tid >> 6] = acc;
    __syncthreads();
    if (tid == 0) {
        float s0 = 0.0f, s1 = 0.0f;
#pragma unroll
        for (int w = 0; w < 8; ++w)  s0 += wsum[w];
#pragma unroll
        for (int w = 8; w < 16; ++w) s1 += wsum[w];
        int n0 = 0, n1 = 0;
#pragma unroll
        for (int s = 0; s < NSEG; ++s) {
            n0 += segcounts[(b * 2) * 4 + s];
            n1 += segcounts[(b * 2 + 1) * 4 + s];
        }
        out[b] = (n0 > 0 && n1 > 0)
                 ? s0 / (float)n0 + s1 / (float)n1
                 : 1.0e6f;
    }
}

extern "C" void kernel_launch(void* const* d_in, const int* in_sizes, int n_in,
                              void* d_out, int out_size, void* d_ws, size_t ws_size,
                              hipStream_t stream) {
    const float* in1 = (const float*)d_in[0];
    const float* in2 = (const float*)d_in[1];
    float* out = (float*)d_out;
    char* ws = (char*)d_ws;
    int* segcounts = (int*)ws;
    float4* pts = (float4*)(ws + 256);
    size_t minoff = 256 + (size_t)8 * HW_ * sizeof(float4);
    unsigned int* minarr = (unsigned int*)(ws + minoff);
    size_t sortoff = minoff + (size_t)8 * HW_ * sizeof(unsigned int);
    float4* sorted = (float4*)(ws + sortoff);
    size_t binoff = sortoff + (size_t)8 * HW_ * sizeof(float4);
    int* binstart = (int*)(ws + binoff);
    size_t histoff = binoff + (size_t)8 * (NBIN + 1) * sizeof(int);
    int* histG = (int*)(ws + histoff);

    hipLaunchKernelGGL(compact_kernel, dim3(NSEG, 8), dim3(1024), 0, stream,
                       in1, in2, segcounts, pts, (uint4*)minarr, histG);
    hipLaunchKernelGGL(scatter_kernel, dim3(NSEG, 8), dim3(1024), 0, stream,
                       segcounts, pts, histG, sorted, binstart);
    hipLaunchKernelGGL(pdist_kernel, dim3(PD_NGRP, 8), dim3(512), 0, stream,
                       sorted, binstart, minarr);
    hipLaunchKernelGGL(reduce_out_kernel, dim3(B_), dim3(1024), 0, stream,
                       segcounts, minarr, out);
}

// Round 16
// 76.903 us; speedup vs baseline: 3.0548x; 1.0224x over previous
//
#include <hip/hip_runtime.h>
#include <math.h>

// Chamfer distance, B=4, H=W=128, HW=16384, threshold 0.1.
//
// r15 post-mortem: best-yet 78.6us = fill(40, harness) + ~38.6 over FOUR
// small kernels -- per-launch fixed cost (gap + wave ramp) is now
// first-order. r16: merge compact+scatter into ONE build_kernel (4->3
// launches). Each (seg,combo) block re-derives the combo's full histogram
// itself (reads 4 float4/thread instead of 1 -- extra reads trivial),
// runs compact's exact own-seg dense-rank scan (identical segcounts +
// slot ids), r15's integer bin wave-scan (identical binstart), and
// scatters its own seg from registers with the identical FMA expressions
// (identical bits). pts buffer, histG round-trip, and the dead minarr
// BIGF-init (pdist plain-stores every active slot since r7) all deleted.
// pdist + reduce VERBATIM r15 -> absmax 0.0.
//
// ws layout (~2.6 MB):
//   [0,128)    int segcounts[8][4]
//   [256,+2MB) float4 sorted[8][HW]  (x, y, z, slot_bits) rho-bucket order
//   [+512KB)   uint minarr[8][HW]    d^2 bits, slot-indexed (no init needed)
//   [+32.8KB)  int binstart[8][1025]

#define B_ 4
#define HW_ 16384
#define THRESH 0.1f
#define BIGF 1e30f
#define EPS_ 1e-12f

#define SEGCAP 4096
#define NSEG 4
#define NBIN 1024
#define BINSCALE 1.0f    // bin = min(1023, rho); width 1, covers rho<1024
#define BINW 1.0f
#define RG 128           // rows per pdist block (2/lane -- window-optimal, r8)
#define NW 8             // waves per pdist block (512 threads)
#define AWIN 768         // phase-A window (cols); needed window ~700-750
#define PD_NGRP 128      // 128 groups x 128 rows covers n_from <= 16384

// ---------------- build: threshold+rank+hist+scan+scatter, one pass --------
__global__ __launch_bounds__(1024)
void build_kernel(const float* __restrict__ in1, const float* __restrict__ in2,
                  int* __restrict__ segcounts, float4* __restrict__ sorted,
                  int* __restrict__ binstartG) {
    int seg = blockIdx.x, combo = blockIdx.y;
    int b = combo >> 1, s = combo & 1;
    int tid = threadIdx.x, lane = tid & 63, wid = tid >> 6;
    const float* in = s ? in2 : in1;

    __shared__ int h[NSEG][NBIN];                // full-combo per-seg hist
    __shared__ int cur[NBIN];
    __shared__ int wtot[16], wpre[17];
    __shared__ int bwt[16];

    for (int i = tid; i < NSEG * NBIN; i += 1024) ((int*)h)[i] = 0;
    __syncthreads();

    // pass 1: histogram ALL segs (identical zz arithmetic as the old
    // compact -> identical bins, deterministic across blocks); cache own
    // seg's w values in registers for the scan + scatter passes.
    float wv0 = 0.f, wv1 = 0.f, wv2 = 0.f, wv3 = 0.f;
    for (int s2 = 0; s2 < NSEG; ++s2) {
        float4 v = ((const float4*)(in + b * HW_))[s2 * (SEGCAP / 4) + tid];
        float w0 = v.x - THRESH, w1 = v.y - THRESH, w2 = v.z - THRESH, w3 = v.w - THRESH;
        if (s2 == seg) { wv0 = w0; wv1 = w1; wv2 = w2; wv3 = w3; }
        float ww[4] = {w0, w1, w2, w3};
        int i0 = s2 * SEGCAP + tid * 4;
#pragma unroll
        for (int u = 0; u < 4; ++u) {
            if (ww[u] > 0.f) {
                int i = i0 + u;
                float qx = (float)(i >> 7) * ww[u];
                float qy = (float)(i & 127) * ww[u];
                float zz = qx * qx + qy * qy;
                int bin = min(NBIN - 1, (int)(sqrtf(zz) * BINSCALE));
                atomicAdd(&h[s2][bin], 1);
            }
        }
    }

    // own-seg dense-rank scan (VERBATIM old compact logic -> same slots)
    int a0 = wv0 > 0.f, a1 = wv1 > 0.f, a2 = wv2 > 0.f, a3 = wv3 > 0.f;
    int c = a0 + a1 + a2 + a3;
    int incl = c;
#pragma unroll
    for (int o = 1; o < 64; o <<= 1) {
        int x = __shfl_up(incl, o, 64);
        if (lane >= o) incl += x;
    }
    int wexcl = incl - c;
    if (lane == 63) wtot[wid] = incl;
    __syncthreads();                             // also fences h atomics
    if (tid == 0) {
        int run = 0;
#pragma unroll
        for (int ww2 = 0; ww2 < 16; ++ww2) { wpre[ww2] = run; run += wtot[ww2]; }
        wpre[16] = run;
    }
    __syncthreads();
    int off = wpre[wid] + wexcl;                 // dense rank within seg
    if (tid == 0) segcounts[combo * 4 + seg] = wpre[16];

    // bin scan (r15 wave scan, integer-exact -> binstart bit-identical)
    int tot = h[0][tid] + h[1][tid] + h[2][tid] + h[3][tid];
    int v2 = tot;
#pragma unroll
    for (int o = 1; o < 64; o <<= 1) {
        int x = __shfl_up(v2, o, 64);
        if (lane >= o) v2 += x;
    }
    if (lane == 63) bwt[wid] = v2;
    __syncthreads();
    if (wid == 0) {
        int wv = (lane < 16) ? bwt[lane] : 0;
#pragma unroll
        for (int o = 1; o < 16; o <<= 1) {
            int x = __shfl_up(wv, o, 64);
            if (lane >= o) wv += x;
        }
        if (lane < 16) bwt[lane] = wv;           // inclusive wave sums
    }
    __syncthreads();
    int bincl = v2 + (wid > 0 ? bwt[wid - 1] : 0);
    int bexcl = bincl - tot;                     // exclusive bin start
    {
        int o2 = bexcl;
        for (int s2 = 0; s2 < seg; ++s2) o2 += h[s2][tid];   // seg-uniform
        cur[tid] = o2;
        if (seg == 0) binstartG[combo * (NBIN + 1) + tid] = bexcl;
    }
    if (seg == 0 && tid == NBIN - 1)
        binstartG[combo * (NBIN + 1) + NBIN] = bincl;   // n_active
    __syncthreads();

    // scatter own seg (identical FMA bits; slot = dense rank as before;
    // within-(seg,bin) order nondeterministic -- proven min-invariant)
    float ww[4] = {wv0, wv1, wv2, wv3};
#pragma unroll
    for (int u = 0; u < 4; ++u) {
        if (ww[u] > 0.f) {
            int i = seg * SEGCAP + tid * 4 + u;
            float qx = (float)(i >> 7) * ww[u];
            float qy = (float)(i & 127) * ww[u];
            float zz = qx * qx + qy * qy;
            int bin = min(NBIN - 1, (int)(sqrtf(zz) * BINSCALE));
            int idx = atomicAdd(&cur[bin], 1);
            sorted[(size_t)combo * HW_ + idx] =
                make_float4(qx, qy, zz, __uint_as_float((unsigned)(seg * SEGCAP + off)));
            ++off;
        }
    }
}

// ---------------- pruned dist: 8 waves/block, 128 rows, 2 phases (r13) -----
__global__ __launch_bounds__(512, 4)   // VGPR cap 128: prefetch fits, no spill
void pdist_kernel(const float4* __restrict__ sorted, const int* __restrict__ binstart,
                  unsigned int* __restrict__ minarr) {
    int grp = blockIdx.x, combo = blockIdx.y;
    int tid = threadIdx.x, lane = tid & 63, w = tid >> 6;
    int tc = combo ^ 1;
    int n_from = binstart[combo * (NBIN + 1) + NBIN];
    int n_to   = binstart[tc * (NBIN + 1) + NBIN];
    if (n_from <= 0 || n_to <= 0) return;        // reduce_out emits sentinel
    int rbase = grp * RG;
    if (rbase >= n_from) return;                 // block-uniform

    const float4* __restrict__ rows = sorted + (size_t)combo * HW_;
    const float4* __restrict__ cols = sorted + (size_t)tc * HW_;

    int r0 = rbase + lane, r1 = rbase + 64 + lane;
    bool v0 = r0 < n_from, v1 = r1 < n_from;
    float4 P0 = rows[min(r0, n_from - 1)];
    float4 P1 = rows[min(r1, n_from - 1)];
    float npx0 = -2.0f * P0.x, npy0 = -2.0f * P0.y, p20 = P0.z;
    float npx1 = -2.0f * P1.x, npy1 = -2.0f * P1.y, p21 = P1.z;
    unsigned int slot0 = __float_as_uint(P0.w);
    unsigned int slot1 = __float_as_uint(P1.w);
    float m0 = BIGF, m1 = BIGF;

    // group rho bounds from BIN BOUNDARIES (order-independent -- r6 fix)
    int blo_r = min(NBIN - 1, (int)(sqrtf(rows[rbase].z) * BINSCALE));
    int bhi_r = min(NBIN - 1, (int)(sqrtf(rows[min(rbase + RG - 1, n_from - 1)].z) * BINSCALE));
    float rho_lo = (float)blo_r * BINW;          // every row rho >= rho_lo
    float rho_hi = (float)(bhi_r + 1) * BINW;    // every row rho <  rho_hi

    // phase-A window centered on the rows' bin-range midpoint (r8)
    int jmid = (binstart[tc * (NBIN + 1) + blo_r]
                + binstart[tc * (NBIN + 1) + min(bhi_r + 1, NBIN)]) >> 1;
    int aHi = min(n_to, jmid + AWIN / 2);
    int aLo = max(0, aHi - AWIN);
    aHi = min(n_to, aLo + AWIN);

    __shared__ __align__(16) float bx[NW][64], by[NW][64], bz[NW][64];
    __shared__ float mW[NW][RG];

    auto ld = [&](int jb) -> float4 {            // clamped batch element load
        int j = jb + lane;
        return (j < n_to) ? cols[j] : make_float4(0.0f, 0.0f, BIGF, 0.0f);
    };
    // stage a preloaded batch into this wave's LDS stripe and min-reduce.
    // Reads are wave-uniform broadcasts (cheap -- r11 proved the LDS pipe
    // is not the bottleneck). Inner math VERBATIM dense -> same bits.
    auto proc = [&](float4 qc) {
        bx[w][lane] = qc.x; by[w][lane] = qc.y; bz[w][lane] = qc.z;
        const float4* X = (const float4*)bx[w];
        const float4* Y = (const float4*)by[w];
        const float4* Z = (const float4*)bz[w];
#pragma unroll
        for (int q4 = 0; q4 < 16; ++q4) {
            float4 qx = X[q4], qy = Y[q4], qz = Z[q4];
            float t0 = fmaf(qy.x, npy0, fmaf(qx.x, npx0, qz.x));
            float u1 = fmaf(qy.y, npy0, fmaf(qx.y, npx0, qz.y));
            m0 = fminf(m0, fminf(t0, u1));
            float u2 = fmaf(qy.z, npy0, fmaf(qx.z, npx0, qz.z));
            float u3 = fmaf(qy.w, npy0, fmaf(qx.w, npx0, qz.w));
            m0 = fminf(m0, fminf(u2, u3));
            float s0 = fmaf(qy.x, npy1, fmaf(qx.x, npx1, qz.x));
            float s1 = fmaf(qy.y, npy1, fmaf(qx.y, npx1, qz.y));
            m1 = fminf(m1, fminf(s0, s1));
            float s2 = fmaf(qy.z, npy1, fmaf(qx.z, npx1, qz.z));
            float s3 = fmaf(qy.w, npy1, fmaf(qx.w, npx1, qz.w));
            m1 = fminf(m1, fminf(s2, s3));
        }
    };

    // ---- phase A: fixed window, wave-interleaved, prefetched ----
    int nbA = (aHi - aLo + 63) >> 6;
    float4 qn = (w < nbA) ? ld(aLo + (w << 6))
                          : make_float4(0.0f, 0.0f, BIGF, 0.0f);
    for (int bi = w; bi < nbA; bi += NW) {
        float4 qc = qn;
        if (bi + NW < nbA) qn = ld(aLo + ((bi + NW) << 6));  // hide under FMAs
        proc(qc);
    }

    mW[w][lane] = m0; mW[w][64 + lane] = m1;
    __syncthreads();
    float c0 = mW[0][lane], c1 = mW[0][64 + lane];
#pragma unroll
    for (int ww = 1; ww < NW; ++ww) {
        c0 = fminf(c0, mW[ww][lane]);
        c1 = fminf(c1, mW[ww][64 + lane]);
    }
    float md0 = v0 ? fmaxf(c0 + p20, 0.0f) : -1.0f;
    float md1 = v1 ? fmaxf(c1 + p21, 0.0f) : -1.0f;
    float g = fmaxf(md0, md1);                   // group md_max via wave reduce
#pragma unroll
    for (int o = 1; o < 64; o <<= 1) g = fmaxf(g, __shfl_xor(g, o));
    // identical in every wave/lane -> identical window on all threads

    // exclusion bound (r6 margin family, proven absmax==0): include every
    // col bin not provably excludable for any row; widen for float slop.
    float S = sqrtf((g + 1.0f) * (1.0f / 0.99f)) * 1.001f;
    int b_lo = max(0, (int)((rho_lo - S) * BINSCALE) - 1);
    int b_hi = min(NBIN, (int)((rho_hi + S) * BINSCALE) + 2);
    int jlo2 = binstart[tc * (NBIN + 1) + b_lo];
    int jhi2 = binstart[tc * (NBIN + 1) + b_hi];

    // ---- phase B: residual [jlo2,aLo) + [aHi,jhi2), check-free, prefetched
    m0 = c0; m1 = c1;
    int nbL = (max(0, aLo - jlo2) + 63) >> 6;
    int nbR = (max(0, jhi2 - aHi) + 63) >> 6;
    int nbB = nbL + nbR;
    auto jbB = [&](int bi) {
        return (bi < nbL) ? (jlo2 + (bi << 6)) : (aHi + ((bi - nbL) << 6));
    };
    qn = (w < nbB) ? ld(jbB(w)) : make_float4(0.0f, 0.0f, BIGF, 0.0f);
    for (int bi = w; bi < nbB; bi += NW) {
        float4 qc = qn;
        if (bi + NW < nbB) qn = ld(jbB(bi + NW));
        proc(qc);                                // overlap cols: min-idempotent
    }
    __syncthreads();                             // phase-A mW reads all done
    mW[w][lane] = m0; mW[w][64 + lane] = m1;
    __syncthreads();
    if (w == 0) {
        float f0 = mW[0][lane], f1 = mW[0][64 + lane];
#pragma unroll
        for (int ww = 1; ww < NW; ++ww) {
            f0 = fminf(f0, mW[ww][lane]);
            f1 = fminf(f1, mW[ww][64 + lane]);
        }
        if (v0) minarr[combo * HW_ + slot0] = __float_as_uint(fmaxf(f0 + p20, 0.0f));
        if (v1) minarr[combo * HW_ + slot1] = __float_as_uint(fmaxf(f1 + p21, 0.0f));
    }
}

// ---------------- reduce (unchanged: defines the absmax==0 sum order) -------
__global__ void reduce_out_kernel(const int* __restrict__ segcounts,
                                  const unsigned int* __restrict__ minarr,
                                  float* __restrict__ out) {
    int b = blockIdx.x;
    int tid = threadIdx.x;
    int d = tid >> 9;
    int t = tid & 511;
    int combo = b * 2 + d;

    float acc = 0.0f;
    for (int s = 0; s < NSEG; ++s) {
        int c = segcounts[combo * 4 + s];
        const unsigned int* ma = minarr + combo * HW_ + s * SEGCAP;
        for (int r = t; r < c; r += 512)
            acc += sqrtf(fmaxf(__uint_as_float(ma[r]), EPS_));
    }
#pragma unroll
    for (int o = 32; o >= 1; o >>= 1) acc += __shfl_down(acc, o);

    __shared__ float wsum[16];
    if ((tid & 63) == 0) wsum[tid >> 6] = acc;
    __syncthreads();
    if (tid == 0) {
        float s0 = 0.0f, s1 = 0.0f;
#pragma unroll
        for (int w = 0; w < 8; ++w)  s0 += wsum[w];
#pragma unroll
        for (int w = 8; w < 16; ++w) s1 += wsum[w];
        int n0 = 0, n1 = 0;
#pragma unroll
        for (int s = 0; s < NSEG; ++s) {
            n0 += segcounts[(b * 2) * 4 + s];
            n1 += segcounts[(b * 2 + 1) * 4 + s];
        }
        out[b] = (n0 > 0 && n1 > 0)
                 ? s0 / (float)n0 + s1 / (float)n1
                 : 1.0e6f;
    }
}

extern "C" void kernel_launch(void* const* d_in, const int* in_sizes, int n_in,
                              void* d_out, int out_size, void* d_ws, size_t ws_size,
                              hipStream_t stream) {
    const float* in1 = (const float*)d_in[0];
    const float* in2 = (const float*)d_in[1];
    float* out = (float*)d_out;
    char* ws = (char*)d_ws;
    int* segcounts = (int*)ws;
    float4* sorted = (float4*)(ws + 256);
    size_t minoff = 256 + (size_t)8 * HW_ * sizeof(float4);
    unsigned int* minarr = (unsigned int*)(ws + minoff);
    size_t binoff = minoff + (size_t)8 * HW_ * sizeof(unsigned int);
    int* binstart = (int*)(ws + binoff);

    hipLaunchKernelGGL(build_kernel, dim3(NSEG, 8), dim3(1024), 0, stream,
                       in1, in2, segcounts, sorted, binstart);
    hipLaunchKernelGGL(pdist_kernel, dim3(PD_NGRP, 8), dim3(512), 0, stream,
                       sorted, binstart, minarr);
    hipLaunchKernelGGL(reduce_out_kernel, dim3(B_), dim3(1024), 0, stream,
                       segcounts, minarr, out);
}